// Round 2
// baseline (248.941 us; speedup 1.0000x reference)
//
#include <hip/hip_runtime.h>

// Fused 3D local-NCC loss. Shapes (2,1,160,192,160) fp32,
// flat = ((n*D + d)*H + h)*W + w. 9x9x9 box window, zero-padded.
//
// One fused kernel: per block a 32(w) x 16(h) x 20(d) output tile.
// March along D over 28 planes: stage halo products in LDS -> W-sum (9-tap,
// LDS) -> H-sum (9-tap, per-thread) -> sliding D-sum via 8-deep register
// ring -> cc -> block reduction. Only ws use: 960 partial floats.

namespace {
constexpr int Wd = 160, Hd = 192, Dd = 160, NB = 2;
constexpr long DSTRIDE = (long)Hd * Wd;        // 30720
constexpr long VOLUME  = (long)Dd * Hd * Wd;   // 4,915,200
constexpr long TOTAL   = VOLUME * NB;          // 9,830,400
constexpr int BW = 32, BH = 16, BD = 20;       // output tile
constexpr int EW = BW + 8, EH = BH + 8;        // 40 x 24 halo extent
constexpr int NWB = Wd / BW, NHB = Hd / BH, NDB = Dd / BD;  // 5,12,8
constexpr int NBLOCKS = NB * NDB * NHB * NWB;  // 960
constexpr int NT = 512;                        // threads/block
constexpr float INV_WV = 1.0f / 729.0f;
}

__global__ __launch_bounds__(NT) void k_ncc(const float* __restrict__ I,
                                            const float* __restrict__ J,
                                            float* __restrict__ partial) {
    __shared__ float raw[5][EH][EW];    // 19,200 B
    __shared__ float wsum[5][EH][BW];   // 15,360 B
    __shared__ float red[NT];           //  2,048 B

    const int tid = threadIdx.x;
    int bx = blockIdx.x;
    const int wb = bx % NWB; bx /= NWB;
    const int hb = bx % NHB; bx /= NHB;
    const int db = bx % NDB; bx /= NDB;
    const int n  = bx;
    const int w0 = wb * BW, h0 = hb * BH, d0 = db * BD;

    const int ty = tid >> 5;          // 0..15
    const int tx = tid & 31;          // 0..31

    float ring[8][5];
#pragma unroll
    for (int k = 0; k < 8; ++k)
#pragma unroll
        for (int c = 0; c < 5; ++c) ring[k][c] = 0.0f;
    float s[5] = {0, 0, 0, 0, 0};
    float acc = 0.0f;

    for (int p = d0 - 4; p <= d0 + BD + 3; ++p) {   // 28 plane steps
        float h5[5] = {0, 0, 0, 0, 0};
        const bool pvalid = (p >= 0) && (p < Dd);   // block-uniform
        if (pvalid) {
            // ---- stage raw products for plane p (halo 40x24) ----
            const long pbase = ((long)n * Dd + p) * DSTRIDE;
            for (int idx = tid; idx < EH * EW; idx += NT) {
                const int yy = idx / EW, xx = idx % EW;
                const int h = h0 - 4 + yy, w = w0 - 4 + xx;
                float vi = 0.0f, vj = 0.0f;
                if ((unsigned)h < (unsigned)Hd && (unsigned)w < (unsigned)Wd) {
                    const long g = pbase + (long)h * Wd + w;
                    vi = I[g];
                    vj = J[g];
                }
                raw[0][yy][xx] = vi;
                raw[1][yy][xx] = vj;
                raw[2][yy][xx] = vi * vi;
                raw[3][yy][xx] = vj * vj;
                raw[4][yy][xx] = vi * vj;
            }
            __syncthreads();
            // ---- 9-tap W-sum: 5ch x 24 rows x 32 outputs = 3840 jobs ----
            for (int idx = tid; idx < 5 * EH * BW; idx += NT) {
                const int ch = idx / (EH * BW);
                const int rem = idx % (EH * BW);
                const int yy = rem / BW, wi = rem % BW;
                float t = 0.0f;
#pragma unroll
                for (int dx = 0; dx < 9; ++dx) t += raw[ch][yy][wi + dx];
                wsum[ch][yy][wi] = t;
            }
            __syncthreads();
            // ---- 9-tap H-sum: thread owns (ty, tx) ----
#pragma unroll
            for (int c = 0; c < 5; ++c) {
                float t = 0.0f;
#pragma unroll
                for (int dy = 0; dy < 9; ++dy) t += wsum[c][ty + dy][tx];
                h5[c] = t;
            }
            __syncthreads();   // protect raw/wsum before next plane
        }
        // ---- sliding D window: s covers planes [p-8, p] (clipped) ----
#pragma unroll
        for (int c = 0; c < 5; ++c) s[c] += h5[c];
        const int dout = p - 4;
        if (dout >= d0) {
            const float cross = s[4] - s[0] * s[1] * INV_WV;
            const float iv    = s[2] - s[0] * s[0] * INV_WV;
            const float jv    = s[3] - s[1] * s[1] * INV_WV;
            acc += (cross * cross) / (iv * jv + 1e-5f);
        }
#pragma unroll
        for (int c = 0; c < 5; ++c) s[c] -= ring[0][c];
#pragma unroll
        for (int k = 0; k < 7; ++k)
#pragma unroll
            for (int c = 0; c < 5; ++c) ring[k][c] = ring[k + 1][c];
#pragma unroll
        for (int c = 0; c < 5; ++c) ring[7][c] = h5[c];
    }

    // ---- block reduction ----
    red[tid] = acc;
    __syncthreads();
    for (int off = NT / 2; off > 0; off >>= 1) {
        if (tid < off) red[tid] += red[tid + off];
        __syncthreads();
    }
    if (tid == 0) partial[blockIdx.x] = red[0];
}

__global__ __launch_bounds__(256) void k_final(const float* __restrict__ partial,
                                               float* __restrict__ out, int nparts) {
    __shared__ double red[256];
    double a = 0.0;
    for (int i = threadIdx.x; i < nparts; i += 256) a += (double)partial[i];
    red[threadIdx.x] = a;
    __syncthreads();
    for (int off = 128; off > 0; off >>= 1) {
        if (threadIdx.x < off) red[threadIdx.x] += red[threadIdx.x + off];
        __syncthreads();
    }
    if (threadIdx.x == 0) out[0] = (float)(-red[0] / (double)TOTAL);
}

extern "C" void kernel_launch(void* const* d_in, const int* in_sizes, int n_in,
                              void* d_out, int out_size, void* d_ws, size_t ws_size,
                              hipStream_t stream) {
    const float* I = (const float*)d_in[0];
    const float* J = (const float*)d_in[1];
    float* partial = (float*)d_ws;          // 960 floats = 3.84 KB
    float* out = (float*)d_out;

    k_ncc<<<NBLOCKS, NT, 0, stream>>>(I, J, partial);
    k_final<<<1, 256, 0, stream>>>(partial, out, NBLOCKS);
}

// Round 3
// 185.649 us; speedup vs baseline: 1.3409x; 1.3409x over previous
//
#include <hip/hip_runtime.h>

// Fused 3D local-NCC loss. Shapes (2,1,160,192,160) fp32,
// flat = ((n*D + d)*H + h)*W + w. 9x9x9 box window, zero-padded.
//
// v3: block owns 32(w) x 16(h) x 28(d) outputs (D padded: 6 blocks of 28
// cover 160, tail clipped). March 36 planes along D, inner 9 unrolled so
// the depth-9 D-history has static indices (no register-ring shuffles).
// Per plane: fused global->register W-slide (3 aligned float4 loads of I,J,
// whole-quad edge predication, 14-add sliding 9-tap per channel) -> b128
// write into double-buffered wsum LDS -> per-voxel 9-tap H-sum (static
// ds_read offsets) -> D sliding window -> cc -> block reduce.

namespace {
constexpr int Wd = 160, Hd = 192, Dd = 160, NB = 2;
constexpr long DSTRIDE = (long)Hd * Wd;        // 30720
constexpr long VOLUME  = (long)Dd * DSTRIDE;   // 4,915,200
constexpr long TOTAL   = VOLUME * NB;          // 9,830,400
constexpr int BW = 32, BH = 16, BD = 28;
constexpr int EH = BH + 8;                     // 24 halo rows
constexpr int NWB = 5, NHB = 12, NDB = 6;      // 6*28=168 covers 160
constexpr int NBLK = NB * NDB * NHB * NWB;     // 720
constexpr int NT = 512;
constexpr int CH = EH * BW;                    // 768 floats per channel
constexpr float INV_WV = 1.0f / 729.0f;
}

__global__ __launch_bounds__(NT, 4) void k_ncc(const float* __restrict__ I,
                                               const float* __restrict__ J,
                                               float* __restrict__ partial) {
    __shared__ float ws[2][5 * CH];   // 30,720 B (double-buffered W-sums)
    __shared__ float red[NT];         //  2,048 B

    const int tid = threadIdx.x;
    int bx = blockIdx.x;
    const int wb = bx % NWB; bx /= NWB;
    const int hb = bx % NHB; bx /= NHB;
    const int db = bx % NDB; bx /= NDB;
    const int n  = bx;
    const int w0 = wb * BW, h0 = hb * BH, d0 = db * BD;
    const long nvol = (long)n * VOLUME;

    // Phase-A job mapping (tid < 192): 24 rows x 8 four-wide segments.
    const int seg = tid & 7;          // 0..7
    const int yy  = tid >> 3;         // 0..63 (valid < 24)
    const int ah  = h0 - 4 + yy;      // input row
    const int wbase = w0 - 4 + (seg << 2);   // multiple of 4
    const bool aJob = (tid < 192);
    const bool ahOk = aJob && ((unsigned)ah < (unsigned)Hd);
    bool qok[3];
#pragma unroll
    for (int q = 0; q < 3; ++q)
        qok[q] = ((unsigned)(wbase + 4 * q) < (unsigned)Wd);
    // LDS write base for phase A (float index), channel stride CH static.
    float* const wa = &ws[0][yy * BW + (seg << 2)];

    // Phase-B ownership: one voxel column (tx, ty).
    const int tx = tid & 31, ty = tid >> 5;   // 32 x 16
    const float* const rb = &ws[0][ty * BW + tx];

    float hist[9][5];
#pragma unroll
    for (int k = 0; k < 9; ++k)
#pragma unroll
        for (int c = 0; c < 5; ++c) hist[k][c] = 0.0f;
    float sa[5] = {0, 0, 0, 0, 0};
    float acc = 0.0f;

    for (int M = 0; M < 4; ++M) {
#pragma unroll
        for (int u = 0; u < 9; ++u) {
            const int t = 9 * M + u;
            const int p = d0 - 4 + t;
            const bool pvalid = ((unsigned)p < (unsigned)Dd);
            const int bufo = (t & 1) * (5 * CH);

            // ---------------- Phase A: global -> W-slide -> LDS ----------
            if (pvalid && aJob) {
                float vi[12], vj[12];
                if (ahOk) {
                    const float* rowI = I + nvol + (long)p * DSTRIDE + (long)ah * Wd;
                    const float* rowJ = J + nvol + (long)p * DSTRIDE + (long)ah * Wd;
#pragma unroll
                    for (int q = 0; q < 3; ++q) {
                        float4 a = qok[q] ? *(const float4*)(rowI + wbase + 4 * q)
                                          : float4{0, 0, 0, 0};
                        float4 b = qok[q] ? *(const float4*)(rowJ + wbase + 4 * q)
                                          : float4{0, 0, 0, 0};
                        vi[4 * q + 0] = a.x; vi[4 * q + 1] = a.y;
                        vi[4 * q + 2] = a.z; vi[4 * q + 3] = a.w;
                        vj[4 * q + 0] = b.x; vj[4 * q + 1] = b.y;
                        vj[4 * q + 2] = b.z; vj[4 * q + 3] = b.w;
                    }
                } else {
#pragma unroll
                    for (int i = 0; i < 12; ++i) { vi[i] = 0.0f; vj[i] = 0.0f; }
                }
                float* const wab = wa + bufo;
#pragma unroll
                for (int c = 0; c < 5; ++c) {
                    float v[12];
#pragma unroll
                    for (int i = 0; i < 12; ++i) {
                        v[i] = (c == 0) ? vi[i]
                             : (c == 1) ? vj[i]
                             : (c == 2) ? vi[i] * vi[i]
                             : (c == 3) ? vj[i] * vj[i]
                                        : vi[i] * vj[i];
                    }
                    float s8 = v[0] + v[1] + v[2] + v[3] + v[4] + v[5] + v[6] + v[7] + v[8];
                    float4 o;
                    o.x = s8;
                    o.y = o.x + (v[9]  - v[0]);
                    o.z = o.y + (v[10] - v[1]);
                    o.w = o.z + (v[11] - v[2]);
                    *(float4*)(wab + c * CH) = o;
                }
            }
            __syncthreads();

            // ---------------- Phase B: H-sum + D-window + cc -------------
            float h5[5];
            if (pvalid) {
                const float* const rbb = rb + bufo;
#pragma unroll
                for (int c = 0; c < 5; ++c) {
                    float tsum = 0.0f;
#pragma unroll
                    for (int dy = 0; dy < 9; ++dy)
                        tsum += rbb[c * CH + dy * BW];
                    h5[c] = tsum;
                }
            } else {
#pragma unroll
                for (int c = 0; c < 5; ++c) h5[c] = 0.0f;
            }
#pragma unroll
            for (int c = 0; c < 5; ++c) sa[c] += h5[c];
            const int dout = d0 + t - 8;
            if (t >= 8 && dout < Dd) {
                const float cross = sa[4] - sa[0] * sa[1] * INV_WV;
                const float iv    = sa[2] - sa[0] * sa[0] * INV_WV;
                const float jv    = sa[3] - sa[1] * sa[1] * INV_WV;
                acc += (cross * cross) / (iv * jv + 1e-5f);
            }
#pragma unroll
            for (int c = 0; c < 5; ++c) sa[c] -= hist[(u + 1) % 9][c];
#pragma unroll
            for (int c = 0; c < 5; ++c) hist[u][c] = h5[c];
        }
    }

    // ---- block reduction ----
    red[tid] = acc;
    __syncthreads();
    for (int off = NT / 2; off > 0; off >>= 1) {
        if (tid < off) red[tid] += red[tid + off];
        __syncthreads();
    }
    if (tid == 0) partial[blockIdx.x] = red[0];
}

__global__ __launch_bounds__(256) void k_final(const float* __restrict__ partial,
                                               float* __restrict__ out, int nparts) {
    __shared__ double red[256];
    double a = 0.0;
    for (int i = threadIdx.x; i < nparts; i += 256) a += (double)partial[i];
    red[threadIdx.x] = a;
    __syncthreads();
    for (int off = 128; off > 0; off >>= 1) {
        if (threadIdx.x < off) red[threadIdx.x] += red[threadIdx.x + off];
        __syncthreads();
    }
    if (threadIdx.x == 0) out[0] = (float)(-red[0] / (double)TOTAL);
}

extern "C" void kernel_launch(void* const* d_in, const int* in_sizes, int n_in,
                              void* d_out, int out_size, void* d_ws, size_t ws_size,
                              hipStream_t stream) {
    const float* I = (const float*)d_in[0];
    const float* J = (const float*)d_in[1];
    float* partial = (float*)d_ws;          // NBLK floats = 2.88 KB
    float* out = (float*)d_out;

    k_ncc<<<NBLK, NT, 0, stream>>>(I, J, partial);
    k_final<<<1, 256, 0, stream>>>(partial, out, NBLK);
}